// Round 6
// baseline (448.592 us; speedup 1.0000x reference)
//
#include <hip/hip_runtime.h>
#include <hip/hip_bf16.h>

#define N_NODES 8192
#define N_EDGES 262144

typedef __attribute__((ext_vector_type(8))) short short8v;
typedef __attribute__((ext_vector_type(4))) float float4v;

static __device__ __forceinline__ unsigned short f2bf(float f) {
    unsigned u = __float_as_uint(f);
    unsigned r = (u + 0x7FFF + ((u >> 16) & 1)) >> 16;   // RNE, finite values
    return (unsigned short)r;
}
static __device__ __forceinline__ float bf2f(unsigned short h) {
    return __uint_as_float(((unsigned)h) << 16);
}
// load 8 fp32 and convert to a bf16 MFMA fragment (bit-identical to pre-cast bf16)
static __device__ __forceinline__ short8v ld_cvt8(const float* p) {
    float4 lo = *(const float4*)p;
    float4 hi = *(const float4*)(p + 4);
    short8v r;
    r[0] = (short)f2bf(lo.x); r[1] = (short)f2bf(lo.y); r[2] = (short)f2bf(lo.z); r[3] = (short)f2bf(lo.w);
    r[4] = (short)f2bf(hi.x); r[5] = (short)f2bf(hi.y); r[6] = (short)f2bf(hi.z); r[7] = (short)f2bf(hi.w);
    return r;
}

// ---------------- hist + gemm1 in ONE dispatch (independent block ranges, no sync needed) -------------
// Blocks 0..1023: edge histogram. Blocks 1024..1535: Y1b = bf16(X @ W1^T), X and W1 read fp32
// directly with in-register bf16 conversion (no cast kernels, no Xb/W1b buffers).

__global__ __launch_bounds__(256) void hist_gemm1_kernel(const int* __restrict__ dst, int* __restrict__ deg,
                                                         const float* __restrict__ X,
                                                         const float* __restrict__ W1,
                                                         unsigned short* __restrict__ Y1b) {
    const int b = blockIdx.x;
    if (b < 1024) {
        int e = b * 256 + threadIdx.x;   // E == 1024*256 exactly
        atomicAdd(&deg[dst[e]], 1);
        return;
    }
    const int g = b - 1024;                      // 512 gemm blocks
    const int bx = g & 255, by = g >> 8;         // 256 x 2
    const int tid = threadIdx.x;
    const int lane = tid & 63;
    const int w = tid >> 6;
    const int r = lane & 15, q = lane >> 4;
    const int m0 = bx * 32;                      // MI=2 tiles of 16
    const int n0 = by * 128 + w * 32;            // NJ=2, WN=4
    const float* Ap = &X[q * 8];
    const float* Bp = &W1[q * 8];
    float4v acc[2][2] = {};
    short8v a[2], bb[2], an[2], bn[2];
#pragma unroll
    for (int i = 0; i < 2; i++) a[i] = ld_cvt8(&Ap[(size_t)(m0 + i * 16 + r) * 512]);
#pragma unroll
    for (int j = 0; j < 2; j++) bb[j] = ld_cvt8(&Bp[(size_t)(n0 + j * 16 + r) * 512]);
    for (int k = 32; k < 512; k += 32) {
#pragma unroll
        for (int i = 0; i < 2; i++) an[i] = ld_cvt8(&Ap[(size_t)(m0 + i * 16 + r) * 512 + k]);
#pragma unroll
        for (int j = 0; j < 2; j++) bn[j] = ld_cvt8(&Bp[(size_t)(n0 + j * 16 + r) * 512 + k]);
#pragma unroll
        for (int i = 0; i < 2; i++)
#pragma unroll
            for (int j = 0; j < 2; j++)
                acc[i][j] = __builtin_amdgcn_mfma_f32_16x16x32_bf16(a[i], bb[j], acc[i][j], 0, 0, 0);
#pragma unroll
        for (int i = 0; i < 2; i++) a[i] = an[i];
#pragma unroll
        for (int j = 0; j < 2; j++) bb[j] = bn[j];
    }
#pragma unroll
    for (int i = 0; i < 2; i++)
#pragma unroll
        for (int j = 0; j < 2; j++)
            acc[i][j] = __builtin_amdgcn_mfma_f32_16x16x32_bf16(a[i], bb[j], acc[i][j], 0, 0, 0);
#pragma unroll
    for (int i = 0; i < 2; i++)
#pragma unroll
        for (int j = 0; j < 2; j++) {
            int col = n0 + j * 16 + r;
#pragma unroll
            for (int t = 0; t < 4; t++) {
                int row = m0 + i * 16 + q * 4 + t;
                Y1b[(size_t)row * 256 + col] = f2bf(acc[i][j][t]);
            }
        }
}

// ---------------- exclusive scan of deg[8192] (1 block x 256, shfl-based); cur = offs ----------------

__global__ __launch_bounds__(256) void scan_kernel(const int* __restrict__ deg, int* __restrict__ offs,
                                                   int* __restrict__ cur) {
    __shared__ int wsum[4];
    int t = threadIdx.x, lane = t & 63, w = t >> 6;
    int v[32];
    int s = 0;
    const int4* dp = (const int4*)&deg[t * 32];
#pragma unroll
    for (int i = 0; i < 8; i++) {
        int4 x = dp[i];
        v[4*i] = x.x; v[4*i+1] = x.y; v[4*i+2] = x.z; v[4*i+3] = x.w;
        s += x.x + x.y + x.z + x.w;
    }
    int incl = s;
#pragma unroll
    for (int d = 1; d < 64; d <<= 1) {
        int u = __shfl_up(incl, d);
        if (lane >= d) incl += u;
    }
    if (lane == 63) wsum[w] = incl;
    __syncthreads();
    int base = 0;
#pragma unroll
    for (int i = 0; i < 4; i++) if (i < w) base += wsum[i];
    int ex = base + incl - s;
    int4* op = (int4*)&offs[t * 32];
    int4* cp = (int4*)&cur[t * 32];
#pragma unroll
    for (int i = 0; i < 8; i++) {
        int4 o;
        o.x = ex; ex += v[4*i];
        o.y = ex; ex += v[4*i+1];
        o.z = ex; ex += v[4*i+2];
        o.w = ex; ex += v[4*i+3];
        op[i] = o; cp[i] = o;
    }
    if (t == 255) offs[N_NODES] = ex;
}

__global__ __launch_bounds__(256) void scatter_kernel(const int* __restrict__ src, const int* __restrict__ dst,
                                                      int* __restrict__ cur, int* __restrict__ csr) {
    int e = blockIdx.x * 256 + threadIdx.x;
    int d = dst[e];
    int p = atomicAdd(&cur[d], 1);
    csr[p] = src[e];
}

// ---------------- agg(Y1)+b1+relu+gemm2 fused, FULL-TLP version ----------------
// 512 blocks x 1024 threads (16 waves). Phase A: wave w aggregates node nb+w (1 node/wave —
// restores R2-level TLP: 32 waves/CU; R5's 4-nodes-serial-per-wave at 8 waves/CU was the
// regression). relu+bf16 -> LDS Hs[16][264]. Phase B: waves 0..7 each compute one 16x16
// N-tile of Z[16,128] = Hs @ W23^T, reading W2/W3 fp32 directly (no W23b cast/buffer).

__global__ __launch_bounds__(1024) void agg_gemm2_kernel(const unsigned short* __restrict__ Yb,
                                                         const int* __restrict__ offs,
                                                         const int* __restrict__ csr,
                                                         const float* __restrict__ bias,
                                                         const float* __restrict__ W2,
                                                         const float* __restrict__ W3,
                                                         unsigned short* __restrict__ Zb) {
    __shared__ unsigned short Hs[16][264];
    const int w = threadIdx.x >> 6, lane = threadIdx.x & 63;
    const int nb = blockIdx.x * 16;
    {
        const int node = nb + w;
        int s = offs[node], e = offs[node + 1];
        float4 acc0 = {0.f, 0.f, 0.f, 0.f}, acc1 = {0.f, 0.f, 0.f, 0.f};
        int i = s;
        for (; i + 3 < e; i += 4) {
            int u0 = csr[i], u1 = csr[i + 1], u2 = csr[i + 2], u3 = csr[i + 3];
            ushort4 v0 = *(const ushort4*)&Yb[(size_t)u0 * 256 + lane * 4];
            ushort4 v1 = *(const ushort4*)&Yb[(size_t)u1 * 256 + lane * 4];
            ushort4 v2 = *(const ushort4*)&Yb[(size_t)u2 * 256 + lane * 4];
            ushort4 v3 = *(const ushort4*)&Yb[(size_t)u3 * 256 + lane * 4];
            acc0.x += bf2f(v0.x) + bf2f(v1.x); acc1.x += bf2f(v2.x) + bf2f(v3.x);
            acc0.y += bf2f(v0.y) + bf2f(v1.y); acc1.y += bf2f(v2.y) + bf2f(v3.y);
            acc0.z += bf2f(v0.z) + bf2f(v1.z); acc1.z += bf2f(v2.z) + bf2f(v3.z);
            acc0.w += bf2f(v0.w) + bf2f(v1.w); acc1.w += bf2f(v2.w) + bf2f(v3.w);
        }
        for (; i < e; i++) {
            int u = csr[i];
            ushort4 v = *(const ushort4*)&Yb[(size_t)u * 256 + lane * 4];
            acc0.x += bf2f(v.x); acc0.y += bf2f(v.y); acc0.z += bf2f(v.z); acc0.w += bf2f(v.w);
        }
        float4 bv = *(const float4*)&bias[lane * 4];
        ushort4 o;
        o.x = f2bf(fmaxf(acc0.x + acc1.x + bv.x, 0.f));
        o.y = f2bf(fmaxf(acc0.y + acc1.y + bv.y, 0.f));
        o.z = f2bf(fmaxf(acc0.z + acc1.z + bv.z, 0.f));
        o.w = f2bf(fmaxf(acc0.w + acc1.w + bv.w, 0.f));
        *(ushort4*)&Hs[w][lane * 4] = o;
    }
    __syncthreads();
    if (w >= 8) return;
    const int r = lane & 15, q = lane >> 4;
    const float* Wrow = (w < 4) ? &W2[(size_t)(w * 16 + r) * 256]
                                : &W3[(size_t)((w - 4) * 16 + r) * 256];
    float4v acc = {};
#pragma unroll
    for (int k = 0; k < 256; k += 32) {
        short8v a = *(const short8v*)&Hs[r][k + q * 8];
        short8v b = ld_cvt8(&Wrow[k + q * 8]);
        acc = __builtin_amdgcn_mfma_f32_16x16x32_bf16(a, b, acc, 0, 0, 0);
    }
#pragma unroll
    for (int t = 0; t < 4; t++)
        Zb[(size_t)(nb + q * 4 + t) * 128 + w * 16 + r] = f2bf(acc[t]);
}

// ---------------- Aggregation over bf16 Z [N,128] -> mu/logvar fp32 (+bias) and bf16 zb [N,64] ----------------

__global__ __launch_bounds__(256) void agg_split_kernel(const unsigned short* __restrict__ Zb,
                                                        const int* __restrict__ offs,
                                                        const int* __restrict__ csr, const float* __restrict__ b2,
                                                        const float* __restrict__ b3, float* __restrict__ mu,
                                                        float* __restrict__ lv, unsigned short* __restrict__ zb) {
    int node = blockIdx.x * 4 + (threadIdx.x >> 6);
    int lane = threadIdx.x & 63;
    int s = offs[node], e = offs[node + 1];
    float2 acc0 = {0.f, 0.f}, acc1 = {0.f, 0.f};
    int i = s;
    for (; i + 3 < e; i += 4) {
        int u0 = csr[i], u1 = csr[i + 1], u2 = csr[i + 2], u3 = csr[i + 3];
        ushort2 v0 = *(const ushort2*)&Zb[(size_t)u0 * 128 + lane * 2];
        ushort2 v1 = *(const ushort2*)&Zb[(size_t)u1 * 128 + lane * 2];
        ushort2 v2 = *(const ushort2*)&Zb[(size_t)u2 * 128 + lane * 2];
        ushort2 v3 = *(const ushort2*)&Zb[(size_t)u3 * 128 + lane * 2];
        acc0.x += bf2f(v0.x) + bf2f(v1.x); acc1.x += bf2f(v2.x) + bf2f(v3.x);
        acc0.y += bf2f(v0.y) + bf2f(v1.y); acc1.y += bf2f(v2.y) + bf2f(v3.y);
    }
    for (; i < e; i++) {
        int u = csr[i];
        ushort2 v = *(const ushort2*)&Zb[(size_t)u * 128 + lane * 2];
        acc0.x += bf2f(v.x); acc0.y += bf2f(v.y);
    }
    float2 acc = {acc0.x + acc1.x, acc0.y + acc1.y};
    int col = lane * 2;
    if (col < 64) {
        acc.x += b2[col]; acc.y += b2[col + 1];
        *(float2*)&mu[(size_t)node * 64 + col] = acc;
        ushort2 q = {f2bf(acc.x), f2bf(acc.y)};
        *(ushort2*)&zb[(size_t)node * 64 + col] = q;
    } else {
        col -= 64;
        acc.x += b3[col]; acc.y += b3[col + 1];
        *(float2*)&lv[(size_t)node * 64 + col] = acc;
    }
}

// ---------------- adj = sigmoid(z z^T): symmetric MFMA, at write-BW floor (R4: 53.7us @ 5.4TB/s) ----

__global__ __launch_bounds__(256) void adj_mfma_sym_kernel(const unsigned short* __restrict__ zb,
                                                           float* __restrict__ out) {
    const int bx = blockIdx.x, by = blockIdx.y;
    if (by > bx) return;                         // lower-left triangle (plus diagonal) only
    const int tid = threadIdx.x;
    const int lane = tid & 63;
    const int wid = tid >> 6;
    const int waveM = wid >> 1, waveN = wid & 1;
    const int m_base = bx * 128 + waveM * 64;
    const int n_base = by * 128 + waveN * 64;
    const int r = lane & 15;
    const int q = lane >> 4;

    short8v a[4][2], b[4][2];
#pragma unroll
    for (int i = 0; i < 4; i++)
#pragma unroll
        for (int s = 0; s < 2; s++) {
            a[i][s] = *(const short8v*)&zb[(size_t)(m_base + i * 16 + r) * 64 + s * 32 + q * 8];
            b[i][s] = *(const short8v*)&zb[(size_t)(n_base + i * 16 + r) * 64 + s * 32 + q * 8];
        }

    float4v acc[4][4] = {};
#pragma unroll
    for (int s = 0; s < 2; s++)
#pragma unroll
        for (int i = 0; i < 4; i++)
#pragma unroll
            for (int j = 0; j < 4; j++)
                acc[i][j] = __builtin_amdgcn_mfma_f32_16x16x32_bf16(a[i][s], b[j][s], acc[i][j], 0, 0, 0);

    const bool mirror = (bx != by);
#pragma unroll
    for (int i = 0; i < 4; i++)
#pragma unroll
        for (int j = 0; j < 4; j++) {
            int col = n_base + j * 16 + r;
            float4 vv;
#pragma unroll
            for (int t = 0; t < 4; t++) {
                int row = m_base + i * 16 + q * 4 + t;
                float v = 1.0f / (1.0f + __expf(-acc[i][j][t]));
                out[(size_t)row * N_NODES + col] = v;
                ((float*)&vv)[t] = v;
            }
            if (mirror) {
                *(float4*)&out[(size_t)col * N_NODES + m_base + i * 16 + q * 4] = vv;
            }
        }
}

// ---------------- launch: 7 dispatches ----------------

extern "C" void kernel_launch(void* const* d_in, const int* in_sizes, int n_in,
                              void* d_out, int out_size, void* d_ws, size_t ws_size,
                              hipStream_t stream) {
    const float* X   = (const float*)d_in[0];
    const int*   src = (const int*)d_in[1];
    const int*   dst = (const int*)d_in[2];
    const float* W1  = (const float*)d_in[3];
    const float* b1  = (const float*)d_in[4];
    const float* W2  = (const float*)d_in[5];
    const float* b2  = (const float*)d_in[6];
    const float* W3  = (const float*)d_in[7];
    const float* b3  = (const float*)d_in[8];

    float* out    = (float*)d_out;
    float* adj    = out;                              // [8192*8192]
    float* mu_out = out + (size_t)N_NODES * N_NODES;  // [8192*64]
    float* lv_out = mu_out + (size_t)N_NODES * 64;    // [8192*64]

    char* ws = (char*)d_ws;
    size_t off = 0;
    auto alloc = [&](size_t bytes) -> void* {
        void* p = ws + off;
        off += (bytes + 1023) & ~(size_t)1023;
        return p;
    };
    int* deg            = (int*)alloc(N_NODES * 4);
    int* cur            = (int*)alloc(N_NODES * 4);
    int* offs           = (int*)alloc((N_NODES + 1) * 4);
    int* csr            = (int*)alloc(N_EDGES * 4);
    unsigned short* Y1b = (unsigned short*)alloc((size_t)N_NODES * 256 * 2);
    unsigned short* Zb  = (unsigned short*)alloc((size_t)N_NODES * 128 * 2);
    unsigned short* zb  = (unsigned short*)alloc((size_t)N_NODES * 64 * 2);

    hipMemsetAsync(deg, 0, N_NODES * sizeof(int), stream);
    // hist (blocks 0..1023) + gemm1 (blocks 1024..1535, X/W1 fp32-direct) — independent, one dispatch
    hist_gemm1_kernel<<<1536, 256, 0, stream>>>(dst, deg, X, W1, Y1b);
    scan_kernel<<<1, 256, 0, stream>>>(deg, offs, cur);
    scatter_kernel<<<N_EDGES / 256, 256, 0, stream>>>(src, dst, cur, csr);
    // agg(Y1)+b1+relu+gemm2 fused, 16 waves/block (full TLP), W2/W3 fp32-direct
    agg_gemm2_kernel<<<N_NODES / 16, 1024, 0, stream>>>(Y1b, offs, csr, b1, W2, W3, Zb);
    // mu/logvar = agg(Zb) + b2/b3 (split); zb = bf16(mu)
    agg_split_kernel<<<N_NODES / 4, 256, 0, stream>>>(Zb, offs, csr, b2, b3, mu_out, lv_out, zb);
    // adj = sigmoid(zb @ zb^T): symmetric, direct scalar + float4 mirror stores
    adj_mfma_sym_kernel<<<dim3(64, 64), 256, 0, stream>>>(zb, adj);
}